// Round 16
// baseline (260.522 us; speedup 1.0000x reference)
//
#include <hip/hip_runtime.h>
#include <hip/hip_bf16.h>
#include <math.h>

#define NE_N 50000
#define NM_N 50000
#define NEDGE 500000
#define EPB 4096
#define NCB 256
#define NBLK ((2 * NEDGE + EPB - 1) / EPB)   // 245
#define NFB 196                              // used coarse buckets

typedef __attribute__((ext_vector_type(8))) short bf16x8;
typedef __attribute__((ext_vector_type(4))) float f32x4;

__device__ __forceinline__ ushort f2bf(float f) {
  uint u = __float_as_uint(f);
  u += 0x7fffu + ((u >> 16) & 1u);   // RNE
  return (ushort)(u >> 16);
}
__device__ __forceinline__ float bfl(uint u) { return __uint_as_float(u << 16); }
__device__ __forceinline__ float bfh(uint u) { return __uint_as_float(u & 0xffff0000u); }

struct GA {  // per-GEMM args
  const ushort* A; const float* Af; const ushort* Wt; const float* bias;
  ushort* Cb; const float* aV; float* alsOut;
  const ushort* VcT; const float* bias4; float* ald4Out; int M; int act;
};
struct AP {  // per-agg args
  const char* hs; const char* als; const char* ald; const float* bias;
  float* out; ushort* outB; const float* Vald; float* aldOut;
};

// ---- composite weights: Wt[b] = bf16T(Win @ Wsrc), bc[b] = bin @ Wsrc ----
__global__ __launch_bounds__(256) void cmm_k(const float* WinE, const float* binE,
    const float* WsE, const float* WinM, const float* binM, const float* WsM,
    ushort* __restrict__ Wt, float* __restrict__ bc) {
  __shared__ float sB[128][128];
  const int b = blockIdx.x >> 3, chunk = blockIdx.x & 7;
  const float* A   = b ? WinM : WinE;
  const float* bin = b ? binM : binE;
  const float* B   = b ? WsM  : WsE;
  const int tid = threadIdx.x;
  for (int i = tid; i < 16384; i += 256) sB[i >> 7][i & 127] = B[i];
  __syncthreads();
  const int r = chunk * 16 + (tid >> 4);
  const int c0 = (tid & 15) * 8;
  float acc[8];
#pragma unroll
  for (int j = 0; j < 8; ++j) acc[j] = 0.f;
  for (int k = 0; k < 128; ++k) {
    float a = A[r * 128 + k];
#pragma unroll
    for (int j = 0; j < 8; ++j) acc[j] = fmaf(a, sB[k][c0 + j], acc[j]);
  }
  ushort* o = Wt + (size_t)b * 16384;
#pragma unroll
  for (int j = 0; j < 8; ++j) o[(c0 + j) * 128 + r] = f2bf(acc[j]);
  if (chunk == 0 && tid < 128) {
    float s = 0.f;
    for (int k = 0; k < 128; ++k) s = fmaf(bin[k], sB[k][tid], s);
    bc[b * 128 + tid] = s;
  }
}

// ---- cast + transpose 3 plain GEMM weights into Wt[2..4] ------------------
__global__ __launch_bounds__(256) void wcast3_k(const float* W0, const float* W1,
                                                const float* W2, ushort* __restrict__ Wt) {
  __shared__ float T[128][129];
  const float* W = (blockIdx.x == 0) ? W0 : (blockIdx.x == 1) ? W1 : W2;
  int tid = threadIdx.x;
  for (int i = tid; i < 16384; i += 256) T[i >> 7][i & 127] = W[i];
  __syncthreads();
  uint* o = (uint*)(Wt + (size_t)(2 + blockIdx.x) * 16384);
  for (int i = tid; i < 8192; i += 256) {
    int n = i >> 6, k2 = (i & 63) << 1;
    o[i] = (uint)f2bf(T[k2][n]) | ((uint)f2bf(T[k2 + 1][n]) << 16);
  }
}

// ---- V[k,h] folds for the 4 dst attention vectors -------------------------
__global__ void vfold4_k(const float* __restrict__ Wem, const float* __restrict__ aem,
                         const float* __restrict__ Wme, const float* __restrict__ ame,
                         float* __restrict__ Vbase) {
  int idx = blockIdx.x;
  int layer = idx >> 1, et = idx & 1;
  const float* W = (et ? Wme : Wem) + layer * 16384;
  const float* a = (et ? ame : aem) + layer * 128;
  float* V = Vbase + idx * 512;
  int t = threadIdx.x;  // 512
  int k = t >> 2, h = t & 3;
  float s = 0.f;
#pragma unroll
  for (int d = 0; d < 32; ++d) s += W[k * 128 + h * 32 + d] * a[h * 32 + d];
  V[k * 4 + h] = s;
}

// ---- composite dst-logit maps: VcT = bf16((Win @ v0)^T), bias4 = bin @ v0 -
__global__ __launch_bounds__(512) void smallprep_k(const float* WinE, const float* binE,
    const float* WinM, const float* binM, const float* __restrict__ Vb,
    ushort* __restrict__ VcTa, ushort* __restrict__ VcTb, float* __restrict__ bias4) {
  const int b = blockIdx.x;
  const float* Win = b ? WinM : WinE;
  const float* bin = b ? binM : binE;
  const float* v0  = b ? Vb : Vb + 512;
  ushort* VcT = b ? VcTb : VcTa;
  int t = threadIdx.x;
  int c = t & 3, k = t >> 2;
  float s = 0.f;
  for (int j = 0; j < 128; ++j) s = fmaf(Win[k * 128 + j], v0[j * 4 + c], s);
  VcT[c * 128 + k] = f2bf(s);
  for (int z = t; z < 12 * 128; z += 512) VcT[512 + z] = 0;
  if (t < 4) {
    float s2 = 0.f;
    for (int j = 0; j < 128; ++j) s2 = fmaf(bin[j], v0[j * 4 + t], s2);
    bias4[b * 4 + t] = s2;
  }
}

// ---- paired MFMA bf16 GEMM, A direct-from-global, W in LDS ----------------
__global__ __launch_bounds__(256) void mgemm2_k(GA ga, GA gb, int nA) {
  const bool isA = (int)blockIdx.x < nA;
  GA g = isA ? ga : gb;
  const int bid = isA ? blockIdx.x : blockIdx.x - nA;
  __shared__ char smem[36864];
  char* sW = smem;
  char* sX = smem + 32768;
  const int tid = threadIdx.x;
  const int row0 = bid * 128;
#pragma unroll
  for (int i = 0; i < 8; ++i) {
    int l = (tid + i * 256) << 4;
    int rl = l >> 8;
    uint4 w = *(const uint4*)((const char*)g.Wt + l);
    *(uint4*)(sW + (l ^ ((rl & 7) << 4))) = w;
  }
  if (g.VcT) {
    int l = tid << 4;
    int rl = l >> 8;
    uint4 v = *(const uint4*)((const char*)g.VcT + l);
    *(uint4*)(sX + (l ^ ((rl & 7) << 4))) = v;
  }
  const int lane = tid & 63, wid = tid >> 6;
  const int l15 = lane & 15, lq = lane >> 4;
  const int wm = wid * 32;
  int r0g = row0 + wm + l15;      if (r0g >= g.M) r0g = g.M - 1;
  int r1g = row0 + wm + 16 + l15; if (r1g >= g.M) r1g = g.M - 1;
  __syncthreads();

  f32x4 acc[2][8];
  f32x4 accd[2];
  {
    f32x4 z = {0.f, 0.f, 0.f, 0.f};
#pragma unroll
    for (int mt = 0; mt < 2; ++mt) {
      accd[mt] = z;
#pragma unroll
      for (int nt = 0; nt < 8; ++nt) acc[mt][nt] = z;
    }
  }
#pragma unroll
  for (int ks = 0; ks < 4; ++ks) {
    bf16x8 af0, af1;
    if (g.Af) {
      float4 a0 = *(const float4*)&g.Af[(size_t)r0g * 128 + ks * 32 + lq * 8];
      float4 a1 = *(const float4*)&g.Af[(size_t)r0g * 128 + ks * 32 + lq * 8 + 4];
      float4 b0 = *(const float4*)&g.Af[(size_t)r1g * 128 + ks * 32 + lq * 8];
      float4 b1 = *(const float4*)&g.Af[(size_t)r1g * 128 + ks * 32 + lq * 8 + 4];
      ushort t0[8] = {f2bf(a0.x), f2bf(a0.y), f2bf(a0.z), f2bf(a0.w),
                      f2bf(a1.x), f2bf(a1.y), f2bf(a1.z), f2bf(a1.w)};
      ushort t1[8] = {f2bf(b0.x), f2bf(b0.y), f2bf(b0.z), f2bf(b0.w),
                      f2bf(b1.x), f2bf(b1.y), f2bf(b1.z), f2bf(b1.w)};
      af0 = *(bf16x8*)t0;
      af1 = *(bf16x8*)t1;
    } else {
      af0 = *(const bf16x8*)((const char*)g.A + (size_t)r0g * 256 + (ks << 6) + (lq << 4));
      af1 = *(const bf16x8*)((const char*)g.A + (size_t)r1g * 256 + (ks << 6) + (lq << 4));
    }
    if (g.VcT) {
      int ov = (l15 << 8) + (ks << 6) + (lq << 4);
      bf16x8 vf = *(const bf16x8*)(sX + (ov ^ ((l15 & 7) << 4)));
      accd[0] = __builtin_amdgcn_mfma_f32_16x16x32_bf16(af0, vf, accd[0], 0, 0, 0);
      accd[1] = __builtin_amdgcn_mfma_f32_16x16x32_bf16(af1, vf, accd[1], 0, 0, 0);
    }
#pragma unroll
    for (int nt = 0; nt < 8; ++nt) {
      int c = (nt << 4) + l15;
      int ob = (c << 8) + (ks << 6) + (lq << 4);
      bf16x8 bf = *(const bf16x8*)(sW + (ob ^ ((c & 7) << 4)));
      acc[0][nt] = __builtin_amdgcn_mfma_f32_16x16x32_bf16(af0, bf, acc[0][nt], 0, 0, 0);
      acc[1][nt] = __builtin_amdgcn_mfma_f32_16x16x32_bf16(af1, bf, acc[1][nt], 0, 0, 0);
    }
  }
  float aVv[8], bv[8];
#pragma unroll
  for (int nt = 0; nt < 8; ++nt) {
    int c = (nt << 4) + l15;
    aVv[nt] = g.aV ? g.aV[c] : 0.f;
    bv[nt] = g.bias ? g.bias[c] : 0.f;
  }
#pragma unroll
  for (int mt = 0; mt < 2; ++mt)
#pragma unroll
    for (int nt = 0; nt < 8; ++nt)
#pragma unroll
      for (int rg = 0; rg < 4; ++rg) {
        float v = acc[mt][nt][rg] + bv[nt];
        if (g.act) v = fmaxf(v, 0.f);
        acc[mt][nt][rg] = v;
      }
  if (g.aV) {
#pragma unroll
    for (int mt = 0; mt < 2; ++mt)
#pragma unroll
      for (int rg = 0; rg < 4; ++rg) {
        float p0 = fmaf(acc[mt][0][rg], aVv[0], acc[mt][1][rg] * aVv[1]);
        float p1 = fmaf(acc[mt][2][rg], aVv[2], acc[mt][3][rg] * aVv[3]);
        float p2 = fmaf(acc[mt][4][rg], aVv[4], acc[mt][5][rg] * aVv[5]);
        float p3 = fmaf(acc[mt][6][rg], aVv[6], acc[mt][7][rg] * aVv[7]);
#pragma unroll
        for (int off = 1; off < 16; off <<= 1) {
          p0 += __shfl_xor(p0, off, 64);
          p1 += __shfl_xor(p1, off, 64);
          p2 += __shfl_xor(p2, off, 64);
          p3 += __shfl_xor(p3, off, 64);
        }
        int r = row0 + wm + mt * 16 + lq * 4 + rg;
        if (l15 == 0 && r < g.M)
          *(float4*)&g.alsOut[(size_t)r * 4] = make_float4(p0, p1, p2, p3);
      }
  }
  if (g.VcT) {
    float b4 = (l15 < 4) ? g.bias4[l15] : 0.f;
#pragma unroll
    for (int mt = 0; mt < 2; ++mt)
#pragma unroll
      for (int rg = 0; rg < 4; ++rg) {
        int r = row0 + wm + mt * 16 + lq * 4 + rg;
        if (l15 < 4 && r < g.M) g.ald4Out[(size_t)r * 4 + l15] = accd[mt][rg] + b4;
      }
  }
  __syncthreads();
#pragma unroll
  for (int mt = 0; mt < 2; ++mt)
#pragma unroll
    for (int nt = 0; nt < 8; ++nt)
#pragma unroll
      for (int rg = 0; rg < 4; ++rg) {
        int r = wm + mt * 16 + lq * 4 + rg;
        int c = (nt << 4) + l15;
        *(ushort*)(sW + ((r << 8) + ((c << 1) ^ ((r & 7) << 4)))) =
            f2bf(acc[mt][nt][rg]);
      }
  __syncthreads();
#pragma unroll
  for (int i = 0; i < 8; ++i) {
    int l = (tid + i * 256) << 4;
    int rl = l >> 8;
    if (row0 + rl < g.M)
      *(uint4*)((char*)g.Cb + (size_t)row0 * 256 + l) =
          *(const uint4*)(sW + (l ^ ((rl & 7) << 4)));
  }
}

// ---- regressor GEMM + fused MLP tail --------------------------------------
__global__ __launch_bounds__(256) void mgemmreg_k(const ushort* __restrict__ A,
    const ushort* __restrict__ Wt, const float* __restrict__ bias, int M,
    const float* __restrict__ W2, const float* __restrict__ b2,
    const float* __restrict__ W3, const float* __restrict__ b3,
    float* __restrict__ pred) {
  __shared__ char smem[49152];
  char* sW = smem;
  char* sX = smem + 32768;
  const int tid = threadIdx.x;
  const int row0 = blockIdx.x * 128;
#pragma unroll
  for (int i = 0; i < 8; ++i) {
    int l = (tid + i * 256) << 4;
    int rl = l >> 8;
    uint4 w = *(const uint4*)((const char*)Wt + l);
    *(uint4*)(sW + (l ^ ((rl & 7) << 4))) = w;
  }
  for (int i = tid; i < 8192; i += 256) {
    int k = i >> 6, c = i & 63;
    *(ushort*)(sX + (((c << 8) + (k << 1)) ^ ((c & 7) << 4))) = f2bf(W2[i]);
  }
  const int lane = tid & 63, wid = tid >> 6;
  const int l15 = lane & 15, lq = lane >> 4;
  const int wm = wid * 32;
  int r0g = row0 + wm + l15;      if (r0g >= M) r0g = M - 1;
  int r1g = row0 + wm + 16 + l15; if (r1g >= M) r1g = M - 1;
  __syncthreads();
  f32x4 acc[2][8];
  {
    f32x4 z = {0.f, 0.f, 0.f, 0.f};
#pragma unroll
    for (int mt = 0; mt < 2; ++mt)
#pragma unroll
      for (int nt = 0; nt < 8; ++nt) acc[mt][nt] = z;
  }
#pragma unroll
  for (int ks = 0; ks < 4; ++ks) {
    bf16x8 af0 = *(const bf16x8*)((const char*)A + (size_t)r0g * 256 + (ks << 6) + (lq << 4));
    bf16x8 af1 = *(const bf16x8*)((const char*)A + (size_t)r1g * 256 + (ks << 6) + (lq << 4));
#pragma unroll
    for (int nt = 0; nt < 8; ++nt) {
      int c = (nt << 4) + l15;
      int ob = (c << 8) + (ks << 6) + (lq << 4);
      bf16x8 bf = *(const bf16x8*)(sW + (ob ^ ((c & 7) << 4)));
      acc[0][nt] = __builtin_amdgcn_mfma_f32_16x16x32_bf16(af0, bf, acc[0][nt], 0, 0, 0);
      acc[1][nt] = __builtin_amdgcn_mfma_f32_16x16x32_bf16(af1, bf, acc[1][nt], 0, 0, 0);
    }
  }
  float bv[8];
#pragma unroll
  for (int nt = 0; nt < 8; ++nt) bv[nt] = bias[(nt << 4) + l15];
  __syncthreads();
#pragma unroll
  for (int mt = 0; mt < 2; ++mt)
#pragma unroll
    for (int nt = 0; nt < 8; ++nt)
#pragma unroll
      for (int rg = 0; rg < 4; ++rg) {
        int r = wm + mt * 16 + lq * 4 + rg;
        int c = (nt << 4) + l15;
        *(ushort*)(sW + ((r << 8) + ((c << 1) ^ ((r & 7) << 4)))) =
            f2bf(fmaxf(acc[mt][nt][rg] + bv[nt], 0.f));
      }
  __syncthreads();
  f32x4 a2[2][4];
  {
    f32x4 z = {0.f, 0.f, 0.f, 0.f};
#pragma unroll
    for (int mt = 0; mt < 2; ++mt)
#pragma unroll
      for (int nt = 0; nt < 4; ++nt) a2[mt][nt] = z;
  }
#pragma unroll
  for (int ks = 0; ks < 4; ++ks) {
    int r0r = wm + l15;
    int o0 = (r0r << 8) + (ks << 6) + (lq << 4);
    bf16x8 af0 = *(const bf16x8*)(sW + (o0 ^ ((r0r & 7) << 4)));
    int r1r = r0r + 16;
    int o1 = (r1r << 8) + (ks << 6) + (lq << 4);
    bf16x8 af1 = *(const bf16x8*)(sW + (o1 ^ ((r1r & 7) << 4)));
#pragma unroll
    for (int nt = 0; nt < 4; ++nt) {
      int c = (nt << 4) + l15;
      int ob = (c << 8) + (ks << 6) + (lq << 4);
      bf16x8 bf = *(const bf16x8*)(sX + (ob ^ ((c & 7) << 4)));
      a2[0][nt] = __builtin_amdgcn_mfma_f32_16x16x32_bf16(af0, bf, a2[0][nt], 0, 0, 0);
      a2[1][nt] = __builtin_amdgcn_mfma_f32_16x16x32_bf16(af1, bf, a2[1][nt], 0, 0, 0);
    }
  }
  float b2v[4], w3v[4];
#pragma unroll
  for (int nt = 0; nt < 4; ++nt) {
    int c = (nt << 4) + l15;
    b2v[nt] = b2[c];
    w3v[nt] = W3[c];
  }
  float b3v = b3[0];
#pragma unroll
  for (int mt = 0; mt < 2; ++mt)
#pragma unroll
    for (int rg = 0; rg < 4; ++rg) {
      float t = 0.f;
#pragma unroll
      for (int nt = 0; nt < 4; ++nt)
        t = fmaf(fmaxf(a2[mt][nt][rg] + b2v[nt], 0.f), w3v[nt], t);
      t += __shfl_xor(t, 1, 64);
      t += __shfl_xor(t, 2, 64);
      t += __shfl_xor(t, 4, 64);
      t += __shfl_xor(t, 8, 64);
      int r = row0 + wm + mt * 16 + lq * 4 + rg;
      if (l15 == 0 && r < M) pred[r] = t + b3v;
    }
}

// ---- sort pass 1: per-block coarse LDS hist --------------------------------
__global__ __launch_bounds__(1024) void histC_k(const int* __restrict__ de,
    const int* __restrict__ dm, int* __restrict__ bhist) {
  __shared__ int lc[NCB];
  const int tid = threadIdx.x, b = blockIdx.x;
  if (tid < NCB) lc[tid] = 0;
  __syncthreads();
  const int e0 = b * EPB;
#pragma unroll
  for (int i = 0; i < 4; ++i) {
    int e = e0 + tid + i * 1024;
    if (e < 2 * NEDGE) {
      int db = (e < NEDGE) ? de[e] : NM_N + dm[e - NEDGE];
      atomicAdd(&lc[db >> 9], 1);
    }
  }
  __syncthreads();
  if (tid < NCB) bhist[tid * NBLK + b] = lc[tid];
}

__global__ __launch_bounds__(256) void scanA_k(const int* __restrict__ cnt,
                                               int* __restrict__ offs,
                                               int* __restrict__ sums, int n) {
  __shared__ int ts[256];
  int tid = threadIdx.x;
  int base = blockIdx.x * 4096 + tid * 16;
  int v[16];
  int s = 0;
#pragma unroll
  for (int i = 0; i < 16; ++i) {
    v[i] = (base + i < n) ? cnt[base + i] : 0;
    s += v[i];
  }
  ts[tid] = s;
  __syncthreads();
  for (int off = 1; off < 256; off <<= 1) {
    int t = (tid >= off) ? ts[tid - off] : 0;
    __syncthreads();
    ts[tid] += t;
    __syncthreads();
  }
  int run = ts[tid] - s;
#pragma unroll
  for (int i = 0; i < 16; ++i) {
    if (base + i < n) offs[base + i] = run;
    run += v[i];
  }
  if (tid == 255) sums[blockIdx.x] = ts[255];
}

__global__ void scanB_k(int* __restrict__ sums, int nchunk) {
  if (threadIdx.x == 0) {
    int acc = 0;
    for (int i = 0; i < nchunk; ++i) {
      int t = sums[i];
      sums[i] = acc;
      acc += t;
    }
    sums[nchunk] = acc;
  }
}

__global__ void scanC_k(int* __restrict__ offs, const int* __restrict__ sums, int n) {
  int i = blockIdx.x * blockDim.x + threadIdx.x;
  if (i < n) offs[i] += sums[i >> 12];
  if (i == 0) offs[n] = sums[(n + 4095) >> 12];
}

// ---- sort pass 2: coarse scatter via per-block LDS ranks -------------------
__global__ __launch_bounds__(1024) void scatterR1_k(const int* __restrict__ se,
    const int* __restrict__ de, const int* __restrict__ sm,
    const int* __restrict__ dm, const int* __restrict__ bbase,
    uint2* __restrict__ tmp) {
  __shared__ int lc[NCB];
  __shared__ int lb[NCB];
  const int tid = threadIdx.x, b = blockIdx.x;
  if (tid < NCB) {
    lc[tid] = 0;
    lb[tid] = bbase[tid * NBLK + b];
  }
  __syncthreads();
  const int e0 = b * EPB;
#pragma unroll
  for (int i = 0; i < 4; ++i) {
    int e = e0 + tid + i * 1024;
    if (e < 2 * NEDGE) {
      int s, db;
      if (e < NEDGE) { s = se[e]; db = de[e]; }
      else { s = sm[e - NEDGE]; db = NM_N + dm[e - NEDGE]; }
      int bk = db >> 9;
      int r = atomicAdd(&lc[bk], 1);
      tmp[lb[bk] + r] = make_uint2((uint)s, (uint)db);
    }
  }
}

// ---- sort pass 3: per-bucket fine sort in LDS, src-banded within dst -------
//  8 scatter sweeps by src>>13 so each dst's edge list is ordered by src band;
//  co-resident agg waves then sweep the src axis in rough sync -> L2-resident
//  gather window.
__global__ __launch_bounds__(1024) void finesort_k(const uint2* __restrict__ tmp,
    const int* __restrict__ bbase, int* __restrict__ offs,
    ushort* __restrict__ ssrc) {
  __shared__ int lh[512];
  __shared__ int lsc[512];
  const int tid = threadIdx.x, b = blockIdx.x;
  const int start = bbase[b * NBLK];
  const int end = bbase[(b + 1) * NBLK];
  if (tid < 512) lh[tid] = 0;
  __syncthreads();
  for (int i = start + tid; i < end; i += 1024)
    atomicAdd(&lh[tmp[i].y & 511], 1);
  __syncthreads();
  if (tid < 512) lsc[tid] = lh[tid];
  __syncthreads();
  for (int off = 1; off < 512; off <<= 1) {
    int t = (tid < 512 && tid >= off) ? lsc[tid - off] : 0;
    __syncthreads();
    if (tid < 512) lsc[tid] += t;
    __syncthreads();
  }
  if (tid < 512) {
    int excl = lsc[tid] - lh[tid];
    int d = b * 512 + tid;
    if (d < 100000) offs[d] = start + excl;
    lh[tid] = excl;
  }
  if (b == NFB - 1 && tid == 0) offs[100000] = 2 * NEDGE;
  __syncthreads();
  for (int band = 0; band < 8; ++band) {   // srcs < 65536 -> bands of 8192
    for (int i = start + tid; i < end; i += 1024) {
      uint2 t = tmp[i];
      if ((int)(t.x >> 13) == band) {
        int r = atomicAdd(&lh[t.y & 511], 1);
        ssrc[start + r] = (ushort)t.x;
      }
    }
    __syncthreads();
  }
}

// ---- merged per-dst softmax aggregation, lane-dedup'd p-compute ------------
__global__ __launch_bounds__(256) void gat_agg2_k(AP pa, AP pb,
    const int* __restrict__ offs, const ushort* __restrict__ ssrc) {
  const int lane = threadIdx.x & 63;
  const int n = (blockIdx.x * 256 + (int)threadIdx.x) >> 6;
  if (n >= 100000) return;
  const bool em = n < NM_N;
  AP g = em ? pa : pb;
  const int nl = em ? n : n - NM_N;
  const int half = lane >> 5, l32 = lane & 31;
  const int hF = l32 >> 3;
  const uint hoff = (uint)(l32 << 3);
  const uint aoffF = (uint)(hF << 2);
  const int hP = l32 & 3;
  const uint aoffP = (uint)(hP << 2);
  const float adF = *(const float*)(g.ald + ((uint)nl * 16u + aoffF));
  const float adP = *(const float*)(g.ald + ((uint)nl * 16u + aoffP));
  const int i0 = offs[n], i1 = offs[n + 1];
  float den = 0.f, a0 = 0.f, a1 = 0.f, a2 = 0.f, a3 = 0.f;
  int base = i0;
  const int shbase = half * 4 + hF;
  for (; base + 8 <= i1; base += 8) {
    int sP = (int)ssrc[base + (l32 >> 2)];
    float e = *(const float*)(g.als + ((uint)sP * 16u + aoffP)) + adP;
    e = fmaxf(e, 0.2f * e);
    float p = __expf(e);
#pragma unroll
    for (int k = 0; k < 4; ++k) {
      float pj = __shfl(p, shbase + k * 8, 64);
      uint sj = (uint)__shfl(sP, (2 * k + half) * 4, 64);
      uint2 u = *(const uint2*)(g.hs + (sj * 256u + hoff));
      a0 = fmaf(pj, bfl(u.x), a0);
      a1 = fmaf(pj, bfh(u.x), a1);
      a2 = fmaf(pj, bfl(u.y), a2);
      a3 = fmaf(pj, bfh(u.y), a3);
      den += pj;
    }
  }
  for (int j = base + half; j < i1; j += 2) {
    uint s0 = (uint)ssrc[j];
    float e = *(const float*)(g.als + (s0 * 16u + aoffF)) + adF;
    e = fmaxf(e, 0.2f * e);
    float p0 = __expf(e);
    uint2 u0 = *(const uint2*)(g.hs + (s0 * 256u + hoff));
    a0 = fmaf(p0, bfl(u0.x), a0);
    a1 = fmaf(p0, bfh(u0.x), a1);
    a2 = fmaf(p0, bfl(u0.y), a2);
    a3 = fmaf(p0, bfh(u0.y), a3);
    den += p0;
  }
  den += __shfl_xor(den, 32, 64);
  a0 += __shfl_xor(a0, 32, 64);
  a1 += __shfl_xor(a1, 32, 64);
  a2 += __shfl_xor(a2, 32, 64);
  a3 += __shfl_xor(a3, 32, 64);
  const float inv = 1.f / (den + 1e-16f);
  const int c0 = 4 * l32;
  float r0 = a0 * inv + g.bias[c0];
  float r1 = a1 * inv + g.bias[c0 + 1];
  float r2 = a2 * inv + g.bias[c0 + 2];
  float r3 = a3 * inv + g.bias[c0 + 3];
  r0 = (r0 > 0.f) ? r0 : expm1f(r0);
  r1 = (r1 > 0.f) ? r1 : expm1f(r1);
  r2 = (r2 > 0.f) ? r2 : expm1f(r2);
  r3 = (r3 > 0.f) ? r3 : expm1f(r3);
  if (half == 0) {
    if (g.out)
      *(float4*)&g.out[(size_t)nl * 128 + c0] = make_float4(r0, r1, r2, r3);
    if (g.outB) {
      uint lo = (uint)f2bf(r0) | ((uint)f2bf(r1) << 16);
      uint hi = (uint)f2bf(r2) | ((uint)f2bf(r3) << 16);
      *(uint2*)&((uint*)g.outB)[(size_t)nl * 64 + 2 * l32] = make_uint2(lo, hi);
    }
  }
  if (g.Vald) {
    float t0 = 0.f, t1 = 0.f, t2 = 0.f, t3 = 0.f;
    if (half == 0) {
      const float4 w0 = *(const float4*)&g.Vald[(c0) * 4];
      const float4 w1 = *(const float4*)&g.Vald[(c0 + 1) * 4];
      const float4 w2 = *(const float4*)&g.Vald[(c0 + 2) * 4];
      const float4 w3 = *(const float4*)&g.Vald[(c0 + 3) * 4];
      t0 = r0 * w0.x + r1 * w1.x + r2 * w2.x + r3 * w3.x;
      t1 = r0 * w0.y + r1 * w1.y + r2 * w2.y + r3 * w3.y;
      t2 = r0 * w0.z + r1 * w1.z + r2 * w2.z + r3 * w3.z;
      t3 = r0 * w0.w + r1 * w1.w + r2 * w2.w + r3 * w3.w;
    }
#pragma unroll
    for (int off = 1; off < 64; off <<= 1) {
      t0 += __shfl_xor(t0, off, 64);
      t1 += __shfl_xor(t1, off, 64);
      t2 += __shfl_xor(t2, off, 64);
      t3 += __shfl_xor(t3, off, 64);
    }
    if (lane == 0)
      *(float4*)&g.aldOut[(size_t)nl * 4] = make_float4(t0, t1, t2, t3);
  }
}

extern "C" void kernel_launch(void* const* d_in, const int* in_sizes, int n_in,
                              void* d_out, int out_size, void* d_ws, size_t ws_size,
                              hipStream_t stream) {
  const float* x_exp   = (const float*)d_in[0];
  const float* x_mat   = (const float*)d_in[1];
  const int*   ei_em   = (const int*)d_in[2];
  const int*   ei_me   = (const int*)d_in[3];
  const float* Win_exp = (const float*)d_in[4];
  const float* bin_exp = (const float*)d_in[5];
  const float* Win_mat = (const float*)d_in[6];
  const float* bin_mat = (const float*)d_in[7];
  const float* Wsrc_em = (const float*)d_in[8];
  const float* Wdst_em = (const float*)d_in[9];
  const float* asrc_em = (const float*)d_in[10];
  const float* adst_em = (const float*)d_in[11];
  const float* b_em    = (const float*)d_in[12];
  const float* Wsrc_me = (const float*)d_in[13];
  const float* Wdst_me = (const float*)d_in[14];
  const float* asrc_me = (const float*)d_in[15];
  const float* adst_me = (const float*)d_in[16];
  const float* b_me    = (const float*)d_in[17];
  const float* Wr1     = (const float*)d_in[18];
  const float* br1     = (const float*)d_in[19];
  const float* Wr2     = (const float*)d_in[20];
  const float* br2     = (const float*)d_in[21];
  const float* Wr3     = (const float*)d_in[22];
  const float* br3     = (const float*)d_in[23];

  float* pred = (float*)d_out;
  float* heO  = pred + NE_N;
  float* hmO  = heO + (size_t)NE_N * 128;

  ushort* bufA  = (ushort*)d_ws;
  ushort* bufB  = bufA + (size_t)6400000;
  ushort* bufC  = bufB + (size_t)6400000;
  ushort* bufD  = bufC + (size_t)6400000;
  uint2*  tmp   = (uint2*)(bufD + (size_t)6400000);
  ushort* Wt    = (ushort*)(tmp + 1000000);
  ushort* VcTa  = Wt + 5 * 16384;
  ushort* VcTb  = VcTa + 2048;
  float*  bc    = (float*)(VcTb + 2048);
  float*  bias4 = bc + 256;
  float*  alsE  = bias4 + 8;
  float*  alsM  = alsE + 200000;
  float*  aldE  = alsM + 200000;
  float*  aldM  = aldE + 200000;
  float*  Vb    = aldM + 200000;
  int*    sums  = (int*)(Vb + 2048);
  int*    offs  = sums + 24;
  int*    bhist = offs + 100001;
  int*    bbase = bhist + NCB * NBLK;
  ushort* ssrc  = (ushort*)(bbase + NCB * NBLK + 4);

  const int* se = ei_em;
  const int* de = ei_em + NEDGE;
  const int* sm = ei_me;
  const int* dm = ei_me + NEDGE;

  const int gGemm = (NE_N + 127) / 128;
  const int gAgg = (100000 + 3) / 4;
  const int nBE = NCB * NBLK;
  const int nChunk2 = (nBE + 4095) / 4096;

  // ---- atomic-free 2-level counting sort (src-banded within dst) ----
  histC_k<<<NBLK, 1024, 0, stream>>>(de, dm, bhist);
  scanA_k<<<nChunk2, 256, 0, stream>>>(bhist, bbase, sums, nBE);
  scanB_k<<<1, 64, 0, stream>>>(sums, nChunk2);
  scanC_k<<<(nBE + 255) / 256, 256, 0, stream>>>(bbase, sums, nBE);
  scatterR1_k<<<NBLK, 1024, 0, stream>>>(se, de, sm, dm, bbase, tmp);
  finesort_k<<<NFB, 1024, 0, stream>>>(tmp, bbase, offs, ssrc);

  // ---- weight prep ----
  cmm_k<<<16, 256, 0, stream>>>(Win_exp, bin_exp, Wsrc_em, Win_mat, bin_mat,
                                Wsrc_me, Wt, bc);
  wcast3_k<<<3, 256, 0, stream>>>(Wsrc_em + 16384, Wsrc_me + 16384, Wr1, Wt);
  vfold4_k<<<4, 512, 0, stream>>>(Wdst_em, adst_em, Wdst_me, adst_me, Vb);
  smallprep_k<<<2, 512, 0, stream>>>(Win_exp, bin_exp, Win_mat, bin_mat, Vb,
                                     VcTa, VcTb, bias4);

  // ---- layer 1 composite GEMMs (paired) ----
  {
    GA a = {nullptr, x_exp, Wt, bc, bufC, asrc_em, alsE, VcTa, bias4, aldE, NE_N, 0};
    GA b = {nullptr, x_mat, Wt + 16384, bc + 128, bufD, asrc_me, alsM, VcTb, bias4 + 4, aldM, NM_N, 0};
    mgemm2_k<<<2 * gGemm, 256, 0, stream>>>(a, b, gGemm);
  }
  // ---- layer 1 aggregations (merged) ----
  {
    AP a = {(const char*)bufC, (const char*)alsE, (const char*)aldM, b_em,
            nullptr, bufA, Vb + 1024, aldM};
    AP b = {(const char*)bufD, (const char*)alsM, (const char*)aldE, b_me,
            nullptr, bufB, Vb + 1536, aldE};
    gat_agg2_k<<<gAgg, 256, 0, stream>>>(a, b, offs, ssrc);
  }
  // ---- layer 2 GEMMs (paired) ----
  {
    GA a = {bufB, nullptr, Wt + 2 * 16384, nullptr, bufC, asrc_em + 128, alsE,
            nullptr, nullptr, nullptr, NE_N, 0};
    GA b = {bufA, nullptr, Wt + 3 * 16384, nullptr, bufD, asrc_me + 128, alsM,
            nullptr, nullptr, nullptr, NM_N, 0};
    mgemm2_k<<<2 * gGemm, 256, 0, stream>>>(a, b, gGemm);
  }
  // ---- layer 2 aggregations (merged) ----
  {
    AP a = {(const char*)bufC, (const char*)alsE, (const char*)aldM, b_em + 128,
            hmO, nullptr, nullptr, nullptr};
    AP b = {(const char*)bufD, (const char*)alsM, (const char*)aldE, b_me + 128,
            heO, bufA, nullptr, nullptr};
    gat_agg2_k<<<gAgg, 256, 0, stream>>>(a, b, offs, ssrc);
  }
  // ---- regressor: fused h1-GEMM + MLP tail -> pred ----
  mgemmreg_k<<<gGemm, 256, 0, stream>>>(bufA, Wt + 4 * 16384, br1, NE_N,
                                        Wr2, br2, Wr3, br3, pred);
}

// Round 17
// 249.680 us; speedup vs baseline: 1.0434x; 1.0434x over previous
//
#include <hip/hip_runtime.h>
#include <hip/hip_bf16.h>
#include <math.h>

#define NE_N 50000
#define NM_N 50000
#define NEDGE 500000
#define EPB 4096
#define NCB 256
#define NBLK ((2 * NEDGE + EPB - 1) / EPB)   // 245
#define NFB 196                              // used coarse buckets

typedef __attribute__((ext_vector_type(8))) short bf16x8;
typedef __attribute__((ext_vector_type(4))) float f32x4;

__device__ __forceinline__ ushort f2bf(float f) {
  uint u = __float_as_uint(f);
  u += 0x7fffu + ((u >> 16) & 1u);   // RNE
  return (ushort)(u >> 16);
}
__device__ __forceinline__ float bfl(uint u) { return __uint_as_float(u << 16); }
__device__ __forceinline__ float bfh(uint u) { return __uint_as_float(u & 0xffff0000u); }

struct GA {  // per-GEMM args
  const ushort* A; const float* Af; const ushort* Wt; const float* bias;
  ushort* Cb; const float* aV; float* alsOut;
  const ushort* VcT; const float* bias4; float* ald4Out; int M; int act;
};
struct AP {  // per-agg args
  const char* hs; const char* als; const char* ald; const float* bias;
  float* out; ushort* outB; const float* Vald; float* aldOut;
};

// ---- composite weights: Wt[b] = bf16T(Win @ Wsrc), bc[b] = bin @ Wsrc ----
__global__ __launch_bounds__(256) void cmm_k(const float* WinE, const float* binE,
    const float* WsE, const float* WinM, const float* binM, const float* WsM,
    ushort* __restrict__ Wt, float* __restrict__ bc) {
  __shared__ float sB[128][128];
  const int b = blockIdx.x >> 3, chunk = blockIdx.x & 7;
  const float* A   = b ? WinM : WinE;
  const float* bin = b ? binM : binE;
  const float* B   = b ? WsM  : WsE;
  const int tid = threadIdx.x;
  for (int i = tid; i < 16384; i += 256) sB[i >> 7][i & 127] = B[i];
  __syncthreads();
  const int r = chunk * 16 + (tid >> 4);
  const int c0 = (tid & 15) * 8;
  float acc[8];
#pragma unroll
  for (int j = 0; j < 8; ++j) acc[j] = 0.f;
  for (int k = 0; k < 128; ++k) {
    float a = A[r * 128 + k];
#pragma unroll
    for (int j = 0; j < 8; ++j) acc[j] = fmaf(a, sB[k][c0 + j], acc[j]);
  }
  ushort* o = Wt + (size_t)b * 16384;
#pragma unroll
  for (int j = 0; j < 8; ++j) o[(c0 + j) * 128 + r] = f2bf(acc[j]);
  if (chunk == 0 && tid < 128) {
    float s = 0.f;
    for (int k = 0; k < 128; ++k) s = fmaf(bin[k], sB[k][tid], s);
    bc[b * 128 + tid] = s;
  }
}

// ---- cast + transpose 3 plain GEMM weights into Wt[2..4] ------------------
__global__ __launch_bounds__(256) void wcast3_k(const float* W0, const float* W1,
                                                const float* W2, ushort* __restrict__ Wt) {
  __shared__ float T[128][129];
  const float* W = (blockIdx.x == 0) ? W0 : (blockIdx.x == 1) ? W1 : W2;
  int tid = threadIdx.x;
  for (int i = tid; i < 16384; i += 256) T[i >> 7][i & 127] = W[i];
  __syncthreads();
  uint* o = (uint*)(Wt + (size_t)(2 + blockIdx.x) * 16384);
  for (int i = tid; i < 8192; i += 256) {
    int n = i >> 6, k2 = (i & 63) << 1;
    o[i] = (uint)f2bf(T[k2][n]) | ((uint)f2bf(T[k2 + 1][n]) << 16);
  }
}

// ---- V[k,h] folds for the 4 dst attention vectors -------------------------
__global__ void vfold4_k(const float* __restrict__ Wem, const float* __restrict__ aem,
                         const float* __restrict__ Wme, const float* __restrict__ ame,
                         float* __restrict__ Vbase) {
  int idx = blockIdx.x;
  int layer = idx >> 1, et = idx & 1;
  const float* W = (et ? Wme : Wem) + layer * 16384;
  const float* a = (et ? ame : aem) + layer * 128;
  float* V = Vbase + idx * 512;
  int t = threadIdx.x;  // 512
  int k = t >> 2, h = t & 3;
  float s = 0.f;
#pragma unroll
  for (int d = 0; d < 32; ++d) s += W[k * 128 + h * 32 + d] * a[h * 32 + d];
  V[k * 4 + h] = s;
}

// ---- composite dst-logit maps: VcT = bf16((Win @ v0)^T), bias4 = bin @ v0 -
__global__ __launch_bounds__(512) void smallprep_k(const float* WinE, const float* binE,
    const float* WinM, const float* binM, const float* __restrict__ Vb,
    ushort* __restrict__ VcTa, ushort* __restrict__ VcTb, float* __restrict__ bias4) {
  const int b = blockIdx.x;
  const float* Win = b ? WinM : WinE;
  const float* bin = b ? binM : binE;
  const float* v0  = b ? Vb : Vb + 512;
  ushort* VcT = b ? VcTb : VcTa;
  int t = threadIdx.x;
  int c = t & 3, k = t >> 2;
  float s = 0.f;
  for (int j = 0; j < 128; ++j) s = fmaf(Win[k * 128 + j], v0[j * 4 + c], s);
  VcT[c * 128 + k] = f2bf(s);
  for (int z = t; z < 12 * 128; z += 512) VcT[512 + z] = 0;
  if (t < 4) {
    float s2 = 0.f;
    for (int j = 0; j < 128; ++j) s2 = fmaf(bin[j], v0[j * 4 + t], s2);
    bias4[b * 4 + t] = s2;
  }
}

// ---- paired MFMA bf16 GEMM, A direct-from-global, W in LDS ----------------
__global__ __launch_bounds__(256) void mgemm2_k(GA ga, GA gb, int nA) {
  const bool isA = (int)blockIdx.x < nA;
  GA g = isA ? ga : gb;
  const int bid = isA ? blockIdx.x : blockIdx.x - nA;
  __shared__ char smem[36864];
  char* sW = smem;
  char* sX = smem + 32768;
  const int tid = threadIdx.x;
  const int row0 = bid * 128;
#pragma unroll
  for (int i = 0; i < 8; ++i) {
    int l = (tid + i * 256) << 4;
    int rl = l >> 8;
    uint4 w = *(const uint4*)((const char*)g.Wt + l);
    *(uint4*)(sW + (l ^ ((rl & 7) << 4))) = w;
  }
  if (g.VcT) {
    int l = tid << 4;
    int rl = l >> 8;
    uint4 v = *(const uint4*)((const char*)g.VcT + l);
    *(uint4*)(sX + (l ^ ((rl & 7) << 4))) = v;
  }
  const int lane = tid & 63, wid = tid >> 6;
  const int l15 = lane & 15, lq = lane >> 4;
  const int wm = wid * 32;
  int r0g = row0 + wm + l15;      if (r0g >= g.M) r0g = g.M - 1;
  int r1g = row0 + wm + 16 + l15; if (r1g >= g.M) r1g = g.M - 1;
  __syncthreads();

  f32x4 acc[2][8];
  f32x4 accd[2];
  {
    f32x4 z = {0.f, 0.f, 0.f, 0.f};
#pragma unroll
    for (int mt = 0; mt < 2; ++mt) {
      accd[mt] = z;
#pragma unroll
      for (int nt = 0; nt < 8; ++nt) acc[mt][nt] = z;
    }
  }
#pragma unroll
  for (int ks = 0; ks < 4; ++ks) {
    bf16x8 af0, af1;
    if (g.Af) {
      float4 a0 = *(const float4*)&g.Af[(size_t)r0g * 128 + ks * 32 + lq * 8];
      float4 a1 = *(const float4*)&g.Af[(size_t)r0g * 128 + ks * 32 + lq * 8 + 4];
      float4 b0 = *(const float4*)&g.Af[(size_t)r1g * 128 + ks * 32 + lq * 8];
      float4 b1 = *(const float4*)&g.Af[(size_t)r1g * 128 + ks * 32 + lq * 8 + 4];
      ushort t0[8] = {f2bf(a0.x), f2bf(a0.y), f2bf(a0.z), f2bf(a0.w),
                      f2bf(a1.x), f2bf(a1.y), f2bf(a1.z), f2bf(a1.w)};
      ushort t1[8] = {f2bf(b0.x), f2bf(b0.y), f2bf(b0.z), f2bf(b0.w),
                      f2bf(b1.x), f2bf(b1.y), f2bf(b1.z), f2bf(b1.w)};
      af0 = *(bf16x8*)t0;
      af1 = *(bf16x8*)t1;
    } else {
      af0 = *(const bf16x8*)((const char*)g.A + (size_t)r0g * 256 + (ks << 6) + (lq << 4));
      af1 = *(const bf16x8*)((const char*)g.A + (size_t)r1g * 256 + (ks << 6) + (lq << 4));
    }
    if (g.VcT) {
      int ov = (l15 << 8) + (ks << 6) + (lq << 4);
      bf16x8 vf = *(const bf16x8*)(sX + (ov ^ ((l15 & 7) << 4)));
      accd[0] = __builtin_amdgcn_mfma_f32_16x16x32_bf16(af0, vf, accd[0], 0, 0, 0);
      accd[1] = __builtin_amdgcn_mfma_f32_16x16x32_bf16(af1, vf, accd[1], 0, 0, 0);
    }
#pragma unroll
    for (int nt = 0; nt < 8; ++nt) {
      int c = (nt << 4) + l15;
      int ob = (c << 8) + (ks << 6) + (lq << 4);
      bf16x8 bf = *(const bf16x8*)(sW + (ob ^ ((c & 7) << 4)));
      acc[0][nt] = __builtin_amdgcn_mfma_f32_16x16x32_bf16(af0, bf, acc[0][nt], 0, 0, 0);
      acc[1][nt] = __builtin_amdgcn_mfma_f32_16x16x32_bf16(af1, bf, acc[1][nt], 0, 0, 0);
    }
  }
  float aVv[8], bv[8];
#pragma unroll
  for (int nt = 0; nt < 8; ++nt) {
    int c = (nt << 4) + l15;
    aVv[nt] = g.aV ? g.aV[c] : 0.f;
    bv[nt] = g.bias ? g.bias[c] : 0.f;
  }
#pragma unroll
  for (int mt = 0; mt < 2; ++mt)
#pragma unroll
    for (int nt = 0; nt < 8; ++nt)
#pragma unroll
      for (int rg = 0; rg < 4; ++rg) {
        float v = acc[mt][nt][rg] + bv[nt];
        if (g.act) v = fmaxf(v, 0.f);
        acc[mt][nt][rg] = v;
      }
  if (g.aV) {
#pragma unroll
    for (int mt = 0; mt < 2; ++mt)
#pragma unroll
      for (int rg = 0; rg < 4; ++rg) {
        float p0 = fmaf(acc[mt][0][rg], aVv[0], acc[mt][1][rg] * aVv[1]);
        float p1 = fmaf(acc[mt][2][rg], aVv[2], acc[mt][3][rg] * aVv[3]);
        float p2 = fmaf(acc[mt][4][rg], aVv[4], acc[mt][5][rg] * aVv[5]);
        float p3 = fmaf(acc[mt][6][rg], aVv[6], acc[mt][7][rg] * aVv[7]);
#pragma unroll
        for (int off = 1; off < 16; off <<= 1) {
          p0 += __shfl_xor(p0, off, 64);
          p1 += __shfl_xor(p1, off, 64);
          p2 += __shfl_xor(p2, off, 64);
          p3 += __shfl_xor(p3, off, 64);
        }
        int r = row0 + wm + mt * 16 + lq * 4 + rg;
        if (l15 == 0 && r < g.M)
          *(float4*)&g.alsOut[(size_t)r * 4] = make_float4(p0, p1, p2, p3);
      }
  }
  if (g.VcT) {
    float b4 = (l15 < 4) ? g.bias4[l15] : 0.f;
#pragma unroll
    for (int mt = 0; mt < 2; ++mt)
#pragma unroll
      for (int rg = 0; rg < 4; ++rg) {
        int r = row0 + wm + mt * 16 + lq * 4 + rg;
        if (l15 < 4 && r < g.M) g.ald4Out[(size_t)r * 4 + l15] = accd[mt][rg] + b4;
      }
  }
  __syncthreads();
#pragma unroll
  for (int mt = 0; mt < 2; ++mt)
#pragma unroll
    for (int nt = 0; nt < 8; ++nt)
#pragma unroll
      for (int rg = 0; rg < 4; ++rg) {
        int r = wm + mt * 16 + lq * 4 + rg;
        int c = (nt << 4) + l15;
        *(ushort*)(sW + ((r << 8) + ((c << 1) ^ ((r & 7) << 4)))) =
            f2bf(acc[mt][nt][rg]);
      }
  __syncthreads();
#pragma unroll
  for (int i = 0; i < 8; ++i) {
    int l = (tid + i * 256) << 4;
    int rl = l >> 8;
    if (row0 + rl < g.M)
      *(uint4*)((char*)g.Cb + (size_t)row0 * 256 + l) =
          *(const uint4*)(sW + (l ^ ((rl & 7) << 4)));
  }
}

// ---- regressor GEMM + fused MLP tail --------------------------------------
__global__ __launch_bounds__(256) void mgemmreg_k(const ushort* __restrict__ A,
    const ushort* __restrict__ Wt, const float* __restrict__ bias, int M,
    const float* __restrict__ W2, const float* __restrict__ b2,
    const float* __restrict__ W3, const float* __restrict__ b3,
    float* __restrict__ pred) {
  __shared__ char smem[49152];
  char* sW = smem;
  char* sX = smem + 32768;
  const int tid = threadIdx.x;
  const int row0 = blockIdx.x * 128;
#pragma unroll
  for (int i = 0; i < 8; ++i) {
    int l = (tid + i * 256) << 4;
    int rl = l >> 8;
    uint4 w = *(const uint4*)((const char*)Wt + l);
    *(uint4*)(sW + (l ^ ((rl & 7) << 4))) = w;
  }
  for (int i = tid; i < 8192; i += 256) {
    int k = i >> 6, c = i & 63;
    *(ushort*)(sX + (((c << 8) + (k << 1)) ^ ((c & 7) << 4))) = f2bf(W2[i]);
  }
  const int lane = tid & 63, wid = tid >> 6;
  const int l15 = lane & 15, lq = lane >> 4;
  const int wm = wid * 32;
  int r0g = row0 + wm + l15;      if (r0g >= M) r0g = M - 1;
  int r1g = row0 + wm + 16 + l15; if (r1g >= M) r1g = M - 1;
  __syncthreads();
  f32x4 acc[2][8];
  {
    f32x4 z = {0.f, 0.f, 0.f, 0.f};
#pragma unroll
    for (int mt = 0; mt < 2; ++mt)
#pragma unroll
      for (int nt = 0; nt < 8; ++nt) acc[mt][nt] = z;
  }
#pragma unroll
  for (int ks = 0; ks < 4; ++ks) {
    bf16x8 af0 = *(const bf16x8*)((const char*)A + (size_t)r0g * 256 + (ks << 6) + (lq << 4));
    bf16x8 af1 = *(const bf16x8*)((const char*)A + (size_t)r1g * 256 + (ks << 6) + (lq << 4));
#pragma unroll
    for (int nt = 0; nt < 8; ++nt) {
      int c = (nt << 4) + l15;
      int ob = (c << 8) + (ks << 6) + (lq << 4);
      bf16x8 bf = *(const bf16x8*)(sW + (ob ^ ((c & 7) << 4)));
      acc[0][nt] = __builtin_amdgcn_mfma_f32_16x16x32_bf16(af0, bf, acc[0][nt], 0, 0, 0);
      acc[1][nt] = __builtin_amdgcn_mfma_f32_16x16x32_bf16(af1, bf, acc[1][nt], 0, 0, 0);
    }
  }
  float bv[8];
#pragma unroll
  for (int nt = 0; nt < 8; ++nt) bv[nt] = bias[(nt << 4) + l15];
  __syncthreads();
#pragma unroll
  for (int mt = 0; mt < 2; ++mt)
#pragma unroll
    for (int nt = 0; nt < 8; ++nt)
#pragma unroll
      for (int rg = 0; rg < 4; ++rg) {
        int r = wm + mt * 16 + lq * 4 + rg;
        int c = (nt << 4) + l15;
        *(ushort*)(sW + ((r << 8) + ((c << 1) ^ ((r & 7) << 4)))) =
            f2bf(fmaxf(acc[mt][nt][rg] + bv[nt], 0.f));
      }
  __syncthreads();
  f32x4 a2[2][4];
  {
    f32x4 z = {0.f, 0.f, 0.f, 0.f};
#pragma unroll
    for (int mt = 0; mt < 2; ++mt)
#pragma unroll
      for (int nt = 0; nt < 4; ++nt) a2[mt][nt] = z;
  }
#pragma unroll
  for (int ks = 0; ks < 4; ++ks) {
    int r0r = wm + l15;
    int o0 = (r0r << 8) + (ks << 6) + (lq << 4);
    bf16x8 af0 = *(const bf16x8*)(sW + (o0 ^ ((r0r & 7) << 4)));
    int r1r = r0r + 16;
    int o1 = (r1r << 8) + (ks << 6) + (lq << 4);
    bf16x8 af1 = *(const bf16x8*)(sW + (o1 ^ ((r1r & 7) << 4)));
#pragma unroll
    for (int nt = 0; nt < 4; ++nt) {
      int c = (nt << 4) + l15;
      int ob = (c << 8) + (ks << 6) + (lq << 4);
      bf16x8 bf = *(const bf16x8*)(sX + (ob ^ ((c & 7) << 4)));
      a2[0][nt] = __builtin_amdgcn_mfma_f32_16x16x32_bf16(af0, bf, a2[0][nt], 0, 0, 0);
      a2[1][nt] = __builtin_amdgcn_mfma_f32_16x16x32_bf16(af1, bf, a2[1][nt], 0, 0, 0);
    }
  }
  float b2v[4], w3v[4];
#pragma unroll
  for (int nt = 0; nt < 4; ++nt) {
    int c = (nt << 4) + l15;
    b2v[nt] = b2[c];
    w3v[nt] = W3[c];
  }
  float b3v = b3[0];
#pragma unroll
  for (int mt = 0; mt < 2; ++mt)
#pragma unroll
    for (int rg = 0; rg < 4; ++rg) {
      float t = 0.f;
#pragma unroll
      for (int nt = 0; nt < 4; ++nt)
        t = fmaf(fmaxf(a2[mt][nt][rg] + b2v[nt], 0.f), w3v[nt], t);
      t += __shfl_xor(t, 1, 64);
      t += __shfl_xor(t, 2, 64);
      t += __shfl_xor(t, 4, 64);
      t += __shfl_xor(t, 8, 64);
      int r = row0 + wm + mt * 16 + lq * 4 + rg;
      if (l15 == 0 && r < M) pred[r] = t + b3v;
    }
}

// ---- sort pass 1: per-block coarse LDS hist --------------------------------
__global__ __launch_bounds__(1024) void histC_k(const int* __restrict__ de,
    const int* __restrict__ dm, int* __restrict__ bhist) {
  __shared__ int lc[NCB];
  const int tid = threadIdx.x, b = blockIdx.x;
  if (tid < NCB) lc[tid] = 0;
  __syncthreads();
  const int e0 = b * EPB;
#pragma unroll
  for (int i = 0; i < 4; ++i) {
    int e = e0 + tid + i * 1024;
    if (e < 2 * NEDGE) {
      int db = (e < NEDGE) ? de[e] : NM_N + dm[e - NEDGE];
      atomicAdd(&lc[db >> 9], 1);
    }
  }
  __syncthreads();
  if (tid < NCB) bhist[tid * NBLK + b] = lc[tid];
}

__global__ __launch_bounds__(256) void scanA_k(const int* __restrict__ cnt,
                                               int* __restrict__ offs,
                                               int* __restrict__ sums, int n) {
  __shared__ int ts[256];
  int tid = threadIdx.x;
  int base = blockIdx.x * 4096 + tid * 16;
  int v[16];
  int s = 0;
#pragma unroll
  for (int i = 0; i < 16; ++i) {
    v[i] = (base + i < n) ? cnt[base + i] : 0;
    s += v[i];
  }
  ts[tid] = s;
  __syncthreads();
  for (int off = 1; off < 256; off <<= 1) {
    int t = (tid >= off) ? ts[tid - off] : 0;
    __syncthreads();
    ts[tid] += t;
    __syncthreads();
  }
  int run = ts[tid] - s;
#pragma unroll
  for (int i = 0; i < 16; ++i) {
    if (base + i < n) offs[base + i] = run;
    run += v[i];
  }
  if (tid == 255) sums[blockIdx.x] = ts[255];
}

__global__ void scanB_k(int* __restrict__ sums, int nchunk) {
  if (threadIdx.x == 0) {
    int acc = 0;
    for (int i = 0; i < nchunk; ++i) {
      int t = sums[i];
      sums[i] = acc;
      acc += t;
    }
    sums[nchunk] = acc;
  }
}

__global__ void scanC_k(int* __restrict__ offs, const int* __restrict__ sums, int n) {
  int i = blockIdx.x * blockDim.x + threadIdx.x;
  if (i < n) offs[i] += sums[i >> 12];
  if (i == 0) offs[n] = sums[(n + 4095) >> 12];
}

// ---- sort pass 2: coarse scatter via per-block LDS ranks -------------------
__global__ __launch_bounds__(1024) void scatterR1_k(const int* __restrict__ se,
    const int* __restrict__ de, const int* __restrict__ sm,
    const int* __restrict__ dm, const int* __restrict__ bbase,
    uint2* __restrict__ tmp) {
  __shared__ int lc[NCB];
  __shared__ int lb[NCB];
  const int tid = threadIdx.x, b = blockIdx.x;
  if (tid < NCB) {
    lc[tid] = 0;
    lb[tid] = bbase[tid * NBLK + b];
  }
  __syncthreads();
  const int e0 = b * EPB;
#pragma unroll
  for (int i = 0; i < 4; ++i) {
    int e = e0 + tid + i * 1024;
    if (e < 2 * NEDGE) {
      int s, db;
      if (e < NEDGE) { s = se[e]; db = de[e]; }
      else { s = sm[e - NEDGE]; db = NM_N + dm[e - NEDGE]; }
      int bk = db >> 9;
      int r = atomicAdd(&lc[bk], 1);
      tmp[lb[bk] + r] = make_uint2((uint)s, (uint)db);
    }
  }
}

// ---- sort pass 3: per-bucket fine sort fully in LDS ------------------------
__global__ __launch_bounds__(1024) void finesort_k(const uint2* __restrict__ tmp,
    const int* __restrict__ bbase, int* __restrict__ offs,
    ushort* __restrict__ ssrc) {
  __shared__ int lh[512];
  __shared__ int lsc[512];
  const int tid = threadIdx.x, b = blockIdx.x;
  const int start = bbase[b * NBLK];
  const int end = bbase[(b + 1) * NBLK];
  if (tid < 512) lh[tid] = 0;
  __syncthreads();
  for (int i = start + tid; i < end; i += 1024)
    atomicAdd(&lh[tmp[i].y & 511], 1);
  __syncthreads();
  if (tid < 512) lsc[tid] = lh[tid];
  __syncthreads();
  for (int off = 1; off < 512; off <<= 1) {
    int t = (tid < 512 && tid >= off) ? lsc[tid - off] : 0;
    __syncthreads();
    if (tid < 512) lsc[tid] += t;
    __syncthreads();
  }
  if (tid < 512) {
    int excl = lsc[tid] - lh[tid];
    int d = b * 512 + tid;
    if (d < 100000) offs[d] = start + excl;
    lh[tid] = excl;
  }
  if (b == NFB - 1 && tid == 0) offs[100000] = 2 * NEDGE;
  __syncthreads();
  for (int i = start + tid; i < end; i += 1024) {
    uint2 t = tmp[i];
    int r = atomicAdd(&lh[t.y & 511], 1);
    ssrc[start + r] = (ushort)t.x;
  }
}

// ---- merged per-dst softmax aggregation, lane-dedup'd p-compute ------------
__global__ __launch_bounds__(256) void gat_agg2_k(AP pa, AP pb,
    const int* __restrict__ offs, const ushort* __restrict__ ssrc) {
  const int lane = threadIdx.x & 63;
  const int n = (blockIdx.x * 256 + (int)threadIdx.x) >> 6;
  if (n >= 100000) return;
  const bool em = n < NM_N;
  AP g = em ? pa : pb;
  const int nl = em ? n : n - NM_N;
  const int half = lane >> 5, l32 = lane & 31;
  const int hF = l32 >> 3;
  const uint hoff = (uint)(l32 << 3);
  const uint aoffF = (uint)(hF << 2);
  const int hP = l32 & 3;
  const uint aoffP = (uint)(hP << 2);
  const float adF = *(const float*)(g.ald + ((uint)nl * 16u + aoffF));
  const float adP = *(const float*)(g.ald + ((uint)nl * 16u + aoffP));
  const int i0 = offs[n], i1 = offs[n + 1];
  float den = 0.f, a0 = 0.f, a1 = 0.f, a2 = 0.f, a3 = 0.f;
  int base = i0;
  const int shbase = half * 4 + hF;
  for (; base + 8 <= i1; base += 8) {
    int sP = (int)ssrc[base + (l32 >> 2)];
    float e = *(const float*)(g.als + ((uint)sP * 16u + aoffP)) + adP;
    e = fmaxf(e, 0.2f * e);
    float p = __expf(e);
#pragma unroll
    for (int k = 0; k < 4; ++k) {
      float pj = __shfl(p, shbase + k * 8, 64);
      uint sj = (uint)__shfl(sP, (2 * k + half) * 4, 64);
      uint2 u = *(const uint2*)(g.hs + (sj * 256u + hoff));
      a0 = fmaf(pj, bfl(u.x), a0);
      a1 = fmaf(pj, bfh(u.x), a1);
      a2 = fmaf(pj, bfl(u.y), a2);
      a3 = fmaf(pj, bfh(u.y), a3);
      den += pj;
    }
  }
  for (int j = base + half; j < i1; j += 2) {
    uint s0 = (uint)ssrc[j];
    float e = *(const float*)(g.als + (s0 * 16u + aoffF)) + adF;
    e = fmaxf(e, 0.2f * e);
    float p0 = __expf(e);
    uint2 u0 = *(const uint2*)(g.hs + (s0 * 256u + hoff));
    a0 = fmaf(p0, bfl(u0.x), a0);
    a1 = fmaf(p0, bfh(u0.x), a1);
    a2 = fmaf(p0, bfl(u0.y), a2);
    a3 = fmaf(p0, bfh(u0.y), a3);
    den += p0;
  }
  den += __shfl_xor(den, 32, 64);
  a0 += __shfl_xor(a0, 32, 64);
  a1 += __shfl_xor(a1, 32, 64);
  a2 += __shfl_xor(a2, 32, 64);
  a3 += __shfl_xor(a3, 32, 64);
  const float inv = 1.f / (den + 1e-16f);
  const int c0 = 4 * l32;
  float r0 = a0 * inv + g.bias[c0];
  float r1 = a1 * inv + g.bias[c0 + 1];
  float r2 = a2 * inv + g.bias[c0 + 2];
  float r3 = a3 * inv + g.bias[c0 + 3];
  r0 = (r0 > 0.f) ? r0 : expm1f(r0);
  r1 = (r1 > 0.f) ? r1 : expm1f(r1);
  r2 = (r2 > 0.f) ? r2 : expm1f(r2);
  r3 = (r3 > 0.f) ? r3 : expm1f(r3);
  if (half == 0) {
    if (g.out)
      *(float4*)&g.out[(size_t)nl * 128 + c0] = make_float4(r0, r1, r2, r3);
    if (g.outB) {
      uint lo = (uint)f2bf(r0) | ((uint)f2bf(r1) << 16);
      uint hi = (uint)f2bf(r2) | ((uint)f2bf(r3) << 16);
      *(uint2*)&((uint*)g.outB)[(size_t)nl * 64 + 2 * l32] = make_uint2(lo, hi);
    }
  }
  if (g.Vald) {
    float t0 = 0.f, t1 = 0.f, t2 = 0.f, t3 = 0.f;
    if (half == 0) {
      const float4 w0 = *(const float4*)&g.Vald[(c0) * 4];
      const float4 w1 = *(const float4*)&g.Vald[(c0 + 1) * 4];
      const float4 w2 = *(const float4*)&g.Vald[(c0 + 2) * 4];
      const float4 w3 = *(const float4*)&g.Vald[(c0 + 3) * 4];
      t0 = r0 * w0.x + r1 * w1.x + r2 * w2.x + r3 * w3.x;
      t1 = r0 * w0.y + r1 * w1.y + r2 * w2.y + r3 * w3.y;
      t2 = r0 * w0.z + r1 * w1.z + r2 * w2.z + r3 * w3.z;
      t3 = r0 * w0.w + r1 * w1.w + r2 * w2.w + r3 * w3.w;
    }
#pragma unroll
    for (int off = 1; off < 64; off <<= 1) {
      t0 += __shfl_xor(t0, off, 64);
      t1 += __shfl_xor(t1, off, 64);
      t2 += __shfl_xor(t2, off, 64);
      t3 += __shfl_xor(t3, off, 64);
    }
    if (lane == 0)
      *(float4*)&g.aldOut[(size_t)nl * 4] = make_float4(t0, t1, t2, t3);
  }
}

extern "C" void kernel_launch(void* const* d_in, const int* in_sizes, int n_in,
                              void* d_out, int out_size, void* d_ws, size_t ws_size,
                              hipStream_t stream) {
  const float* x_exp   = (const float*)d_in[0];
  const float* x_mat   = (const float*)d_in[1];
  const int*   ei_em   = (const int*)d_in[2];
  const int*   ei_me   = (const int*)d_in[3];
  const float* Win_exp = (const float*)d_in[4];
  const float* bin_exp = (const float*)d_in[5];
  const float* Win_mat = (const float*)d_in[6];
  const float* bin_mat = (const float*)d_in[7];
  const float* Wsrc_em = (const float*)d_in[8];
  const float* Wdst_em = (const float*)d_in[9];
  const float* asrc_em = (const float*)d_in[10];
  const float* adst_em = (const float*)d_in[11];
  const float* b_em    = (const float*)d_in[12];
  const float* Wsrc_me = (const float*)d_in[13];
  const float* Wdst_me = (const float*)d_in[14];
  const float* asrc_me = (const float*)d_in[15];
  const float* adst_me = (const float*)d_in[16];
  const float* b_me    = (const float*)d_in[17];
  const float* Wr1     = (const float*)d_in[18];
  const float* br1     = (const float*)d_in[19];
  const float* Wr2     = (const float*)d_in[20];
  const float* br2     = (const float*)d_in[21];
  const float* Wr3     = (const float*)d_in[22];
  const float* br3     = (const float*)d_in[23];

  float* pred = (float*)d_out;
  float* heO  = pred + NE_N;
  float* hmO  = heO + (size_t)NE_N * 128;

  ushort* bufA  = (ushort*)d_ws;
  ushort* bufB  = bufA + (size_t)6400000;
  ushort* bufC  = bufB + (size_t)6400000;
  ushort* bufD  = bufC + (size_t)6400000;
  uint2*  tmp   = (uint2*)(bufD + (size_t)6400000);
  ushort* Wt    = (ushort*)(tmp + 1000000);
  ushort* VcTa  = Wt + 5 * 16384;
  ushort* VcTb  = VcTa + 2048;
  float*  bc    = (float*)(VcTb + 2048);
  float*  bias4 = bc + 256;
  float*  alsE  = bias4 + 8;
  float*  alsM  = alsE + 200000;
  float*  aldE  = alsM + 200000;
  float*  aldM  = aldE + 200000;
  float*  Vb    = aldM + 200000;
  int*    sums  = (int*)(Vb + 2048);
  int*    offs  = sums + 24;
  int*    bhist = offs + 100001;
  int*    bbase = bhist + NCB * NBLK;
  ushort* ssrc  = (ushort*)(bbase + NCB * NBLK + 4);

  const int* se = ei_em;
  const int* de = ei_em + NEDGE;
  const int* sm = ei_me;
  const int* dm = ei_me + NEDGE;

  const int gGemm = (NE_N + 127) / 128;
  const int gAgg = (100000 + 3) / 4;
  const int nBE = NCB * NBLK;
  const int nChunk2 = (nBE + 4095) / 4096;

  // ---- atomic-free 2-level counting sort ----
  histC_k<<<NBLK, 1024, 0, stream>>>(de, dm, bhist);
  scanA_k<<<nChunk2, 256, 0, stream>>>(bhist, bbase, sums, nBE);
  scanB_k<<<1, 64, 0, stream>>>(sums, nChunk2);
  scanC_k<<<(nBE + 255) / 256, 256, 0, stream>>>(bbase, sums, nBE);
  scatterR1_k<<<NBLK, 1024, 0, stream>>>(se, de, sm, dm, bbase, tmp);
  finesort_k<<<NFB, 1024, 0, stream>>>(tmp, bbase, offs, ssrc);

  // ---- weight prep ----
  cmm_k<<<16, 256, 0, stream>>>(Win_exp, bin_exp, Wsrc_em, Win_mat, bin_mat,
                                Wsrc_me, Wt, bc);
  wcast3_k<<<3, 256, 0, stream>>>(Wsrc_em + 16384, Wsrc_me + 16384, Wr1, Wt);
  vfold4_k<<<4, 512, 0, stream>>>(Wdst_em, adst_em, Wdst_me, adst_me, Vb);
  smallprep_k<<<2, 512, 0, stream>>>(Win_exp, bin_exp, Win_mat, bin_mat, Vb,
                                     VcTa, VcTb, bias4);

  // ---- layer 1 composite GEMMs (paired) ----
  {
    GA a = {nullptr, x_exp, Wt, bc, bufC, asrc_em, alsE, VcTa, bias4, aldE, NE_N, 0};
    GA b = {nullptr, x_mat, Wt + 16384, bc + 128, bufD, asrc_me, alsM, VcTb, bias4 + 4, aldM, NM_N, 0};
    mgemm2_k<<<2 * gGemm, 256, 0, stream>>>(a, b, gGemm);
  }
  // ---- layer 1 aggregations (merged) ----
  {
    AP a = {(const char*)bufC, (const char*)alsE, (const char*)aldM, b_em,
            nullptr, bufA, Vb + 1024, aldM};
    AP b = {(const char*)bufD, (const char*)alsM, (const char*)aldE, b_me,
            nullptr, bufB, Vb + 1536, aldE};
    gat_agg2_k<<<gAgg, 256, 0, stream>>>(a, b, offs, ssrc);
  }
  // ---- layer 2 GEMMs (paired) ----
  {
    GA a = {bufB, nullptr, Wt + 2 * 16384, nullptr, bufC, asrc_em + 128, alsE,
            nullptr, nullptr, nullptr, NE_N, 0};
    GA b = {bufA, nullptr, Wt + 3 * 16384, nullptr, bufD, asrc_me + 128, alsM,
            nullptr, nullptr, nullptr, NM_N, 0};
    mgemm2_k<<<2 * gGemm, 256, 0, stream>>>(a, b, gGemm);
  }
  // ---- layer 2 aggregations (merged) ----
  {
    AP a = {(const char*)bufC, (const char*)alsE, (const char*)aldM, b_em + 128,
            hmO, nullptr, nullptr, nullptr};
    AP b = {(const char*)bufD, (const char*)alsM, (const char*)aldE, b_me + 128,
            heO, bufA, nullptr, nullptr};
    gat_agg2_k<<<gAgg, 256, 0, stream>>>(a, b, offs, ssrc);
  }
  // ---- regressor: fused h1-GEMM + MLP tail -> pred ----
  mgemmreg_k<<<gGemm, 256, 0, stream>>>(bufA, Wt + 4 * 16384, br1, NE_N,
                                        Wr2, br2, Wr3, br3, pred);
}